// Round 7
// baseline (145.346 us; speedup 1.0000x reference)
//
#include <hip/hip_runtime.h>
#include <stdint.h>

// C = binarize(X) @ binarize(W), exact via MX-fp4 (+-1) scaled MFMA.
// X: 8192x4096 f32, W: 4096x4096 f32, C: 8192x4096 f32.
// fp4 e2m1: +1.0 = 0x2, -1.0 = 0xA. Scale E8M0 127 = 1.0 (word 0x7F7F7F7F).
//
// R7: 256x256 tile, 8 waves (2x4), BK=256 fp4, double-buffered LDS (128 KiB),
// 4-phase pipelined K-tile (reads one phase ahead, staging front-loaded).
// MFMA shape back to 16x16x128 with R5's verified ZERO-bank-conflict read
// geometry (rows keyed by lane&15, slot (s*4+g)^(row&7)); R6's 32x32 rows
// (lane&31, one slot/half-wave) was structurally 4-way conflicted (6.29M).
#define MDIM 8192
#define NDIM 4096
#define KDIM 4096
#define KB2  (KDIM / 2)     // 2048 B per packed row (2 fp4/byte)
#define BKB  128            // K-tile bytes = 256 fp4 elems
#define NKT  (KDIM / 256)   // 16 K-tiles

#define BM 256
#define BN 256
#define ABUF      32768     // A region per buffer: 256 rows x 128 B
#define BUFSTRIDE 65536     // A + B per buffer

typedef __attribute__((ext_vector_type(4))) int   i32x4;
typedef __attribute__((ext_vector_type(8))) int   i32x8;
typedef __attribute__((ext_vector_type(4))) float f32x4;

__device__ __forceinline__ void gload16(const void* g, void* l) {
    __builtin_amdgcn_global_load_lds(
        (const __attribute__((address_space(1))) void*)g,
        (__attribute__((address_space(3))) void*)l, 16, 0, 0);
}

__device__ __forceinline__ i32x8 pad8(i32x4 v) {
    i32x8 r;
    r[0] = v[0]; r[1] = v[1]; r[2] = v[2]; r[3] = v[3];
    r[4] = 0;    r[5] = 0;    r[6] = 0;    r[7] = 0;
    return r;
}

// scale 1.0 everywhere; fp4 format code = 4 for both operands.
#define MFMA_FP4(a, b, c)                                                   \
    __builtin_amdgcn_mfma_scale_f32_16x16x128_f8f6f4(                        \
        (a), (b), (c), 4, 4, 0, 0x7F7F7F7F, 0, 0x7F7F7F7F)

// ---------------- pack X -> A4 [M][K/2] fp4 nibbles (BW-bound) ---------------
__global__ __launch_bounds__(256) void pack_a4_kernel(const float* __restrict__ X,
                                                      uint8_t* __restrict__ A4) {
    size_t gt = (size_t)blockIdx.x * 256 + threadIdx.x;
    const float4* x4 = (const float4*)X + gt * 4;
    uint32_t out[2] = {0, 0};
#pragma unroll
    for (int q = 0; q < 4; ++q) {
        float4 v = x4[q];
        uint32_t b0 = (v.x >= 0.f ? 0x2u : 0xAu) | ((v.y >= 0.f ? 0x2u : 0xAu) << 4);
        uint32_t b1 = (v.z >= 0.f ? 0x2u : 0xAu) | ((v.w >= 0.f ? 0x2u : 0xAu) << 4);
        out[q >> 1] |= (b0 | (b1 << 8)) << ((q & 1) * 16);
    }
    ((uint2*)A4)[gt] = make_uint2(out[0], out[1]);
}

// ---------------- pack W -> B4T [N][K/2] fp4 nibbles, transposed -------------
__global__ __launch_bounds__(256) void pack_b4t_kernel(const float* __restrict__ W,
                                                       uint8_t* __restrict__ B4) {
    __shared__ uint8_t t[64][72];                 // sign nibbles, +8 pad
    const int tid = threadIdx.x;
    const int k0 = blockIdx.y * 64, n0 = blockIdx.x * 64;
#pragma unroll
    for (int r = 0; r < 4; ++r) {
        int e  = r * 1024 + tid * 4;
        int k  = e >> 6;
        int nn = e & 63;
        float4 v = *(const float4*)&W[(size_t)(k0 + k) * NDIM + n0 + nn];
        uint32_t b0 = (v.x >= 0.f) ? 0x2u : 0xAu;
        uint32_t b1 = (v.y >= 0.f) ? 0x2u : 0xAu;
        uint32_t b2 = (v.z >= 0.f) ? 0x2u : 0xAu;
        uint32_t b3 = (v.w >= 0.f) ? 0x2u : 0xAu;
        *(uint32_t*)&t[k][nn] = b0 | (b1 << 8) | (b2 << 16) | (b3 << 24);
    }
    __syncthreads();
    const int n = tid >> 2, kc = tid & 3;         // 16 k-elems -> 8 bytes each
    uint32_t w[2] = {0, 0};
#pragma unroll
    for (int b = 0; b < 8; ++b) {
        int k = kc * 16 + b * 2;
        uint32_t byte = (uint32_t)t[k][n] | ((uint32_t)t[k + 1][n] << 4);
        w[b >> 2] |= byte << ((b & 3) * 8);
    }
    *(uint2*)&B4[(size_t)(n0 + n) * KB2 + k0 / 2 + kc * 8] = make_uint2(w[0], w[1]);
}

// ---------------- main: fp4 MFMA GEMM, 256x256, 4-phase pipelined ------------
__global__ __launch_bounds__(512, 2) void binmm_fp4_kernel(const uint8_t* __restrict__ A4,
                                                           const uint8_t* __restrict__ B4,
                                                           float* __restrict__ C) {
    __shared__ uint8_t lds[2 * BUFSTRIDE];        // 128 KiB

    const int tid = threadIdx.x, lane = tid & 63, wid = tid >> 6;
    const int wr = wid >> 2, wc = wid & 3;        // 2x4 waves; wave tile 128x64
    const int l15 = lane & 15, g = (lane >> 4) & 3;
    const int m0 = blockIdx.y * BM, n0 = blockIdx.x * BN;

    // staging: rows tid>>3 (+p*64), slot tid&7; LDS dest linear (G21),
    // source slot pre-swizzled with ^(row&7).
    const int srow  = tid >> 3;
    const int sslot = tid & 7;
    const uint8_t* gA[4];
    const uint8_t* gB[4];
#pragma unroll
    for (int p = 0; p < 4; ++p) {
        int row = srow + p * 64;
        int ss  = (sslot ^ (row & 7)) * 16;
        gA[p] = A4 + (size_t)(m0 + row) * KB2 + ss;
        gB[p] = B4 + (size_t)(n0 + row) * KB2 + ss;
    }

    f32x4 acc[8][4];
#pragma unroll
    for (int m = 0; m < 8; ++m)
#pragma unroll
        for (int n = 0; n < 4; ++n) acc[m][n] = (f32x4){0.f, 0.f, 0.f, 0.f};

    auto stageA = [&](int nxt) {
#pragma unroll
        for (int p = 0; p < 4; ++p) {
            gload16(gA[p], lds + nxt + tid * 16 + p * 8192);
            gA[p] += BKB;
        }
    };
    auto stageB = [&](int nxt) {
#pragma unroll
        for (int p = 0; p < 4; ++p) {
            gload16(gB[p], lds + nxt + ABUF + tid * 16 + p * 8192);
            gB[p] += BKB;
        }
    };

    // fragment reads, R5's verified 0-conflict geometry: row keyed by l15,
    // slot = (s*4+g)^(row&7). half=0 -> A rows wr*128+{0..63}, half=1 -> +64.
#define RD_A(dst, buf, s, half) do {                                           \
        _Pragma("unroll")                                                      \
        for (int mf = 0; mf < 4; ++mf) {                                       \
            int row = wr * 128 + (half) * 64 + mf * 16 + l15;                  \
            dst[mf] = *(const i32x4*)(lds + (buf) + row * 128 +                \
                                      ((((s) * 4 + g) ^ (row & 7)) * 16));     \
        }                                                                      \
    } while (0)
#define RD_B(dst, buf, s) do {                                                 \
        _Pragma("unroll")                                                      \
        for (int nf = 0; nf < 4; ++nf) {                                       \
            int row = wc * 64 + nf * 16 + l15;                                 \
            dst[nf] = *(const i32x4*)(lds + (buf) + ABUF + row * 128 +         \
                                      ((((s) * 4 + g) ^ (row & 7)) * 16));     \
        }                                                                      \
    } while (0)
    // 16-MFMA cluster: A-half `half` x all 4 B frags, acc rows half*4..+3
#define CLUSTER(AS, BS, half) do {                                             \
        __builtin_amdgcn_s_setprio(1);                                         \
        _Pragma("unroll")                                                      \
        for (int mf = 0; mf < 4; ++mf) {                                       \
            i32x8 a8 = pad8(AS[mf]);                                           \
            acc[(half) * 4 + mf][0] = MFMA_FP4(a8, pad8(BS[0]), acc[(half) * 4 + mf][0]); \
            acc[(half) * 4 + mf][1] = MFMA_FP4(a8, pad8(BS[1]), acc[(half) * 4 + mf][1]); \
            acc[(half) * 4 + mf][2] = MFMA_FP4(a8, pad8(BS[2]), acc[(half) * 4 + mf][2]); \
            acc[(half) * 4 + mf][3] = MFMA_FP4(a8, pad8(BS[3]), acc[(half) * 4 + mf][3]); \
        }                                                                      \
        __builtin_amdgcn_s_setprio(0);                                         \
    } while (0)

    i32x4 aLo[4], aHi[4], bC[4];                  // current s-step frags
    i32x4 aLoN[4], aHiN[4], bN[4];                // next s-step frags

    // one K-tile: 4 phases; entering, {aLo,aHi,bC} hold s=0 frags of `cur`.
    auto tile = [&](int cur, int nxt, bool do_stage, bool rd_next) {
        // phase 0: prefetch s=1 (B + A-lo), stage A, compute (lo, s=0)
        RD_B(bN, cur, 1);
        RD_A(aLoN, cur, 1, 0);
        if (do_stage) stageA(nxt);
        CLUSTER(aLo, bC, 0);
        // phase 1: prefetch s=1 (A-hi), stage B, compute (hi, s=0)
        RD_A(aHiN, cur, 1, 1);
        if (do_stage) stageB(nxt);
        CLUSTER(aHi, bC, 1);
        // phase 2/3: compute s=1
        CLUSTER(aLoN, bN, 0);
        CLUSTER(aHiN, bN, 1);
        // barrier: publishes cur free; drains stages into nxt (vmcnt at barrier)
        __syncthreads();
        if (rd_next) {                            // next tile's s=0 frags
            RD_B(bC, nxt, 0);
            RD_A(aLo, nxt, 0, 0);
            RD_A(aHi, nxt, 0, 1);
        }
    };

    // prologue: stage tile 0 into buffer 0, then read its s=0 frags
    stageA(0); stageB(0);
    __syncthreads();
    RD_B(bC, 0, 0);
    RD_A(aLo, 0, 0, 0);
    RD_A(aHi, 0, 0, 1);

#pragma unroll 1
    for (int tt = 0; tt < NKT / 2 - 1; ++tt) {    // tiles 0..13
        tile(0, BUFSTRIDE, true, true);
        tile(BUFSTRIDE, 0, true, true);
    }
    tile(0, BUFSTRIDE, true, true);               // tile 14 (stages tile 15)
    tile(BUFSTRIDE, 0, false, false);             // tile 15

    // epilogue: C/D 16x16 layout: col = lane&15, row = (lane>>4)*4 + reg
#pragma unroll
    for (int mf = 0; mf < 8; ++mf) {
#pragma unroll
        for (int nf = 0; nf < 4; ++nf) {
            size_t cc = (size_t)(n0 + wc * 64 + nf * 16 + l15);
            int rbase = m0 + wr * 128 + mf * 16 + g * 4;
#pragma unroll
            for (int reg = 0; reg < 4; ++reg)
                C[(size_t)(rbase + reg) * NDIM + cc] = acc[mf][nf][reg];
        }
    }
}

// =============================================================================
extern "C" void kernel_launch(void* const* d_in, const int* in_sizes, int n_in,
                              void* d_out, int out_size, void* d_ws, size_t ws_size,
                              hipStream_t stream) {
    const float* x = (const float*)d_in[0];   // [8192][4096]
    const float* w = (const float*)d_in[1];   // [4096][4096]
    float* out = (float*)d_out;               // [8192][4096]

    // workspace: A4 [M][K/2] (16 MiB) then B4T [N][K/2] (8 MiB)
    uint8_t* A4 = (uint8_t*)d_ws;
    uint8_t* B4 = (uint8_t*)d_ws + (size_t)MDIM * KB2;

    pack_a4_kernel<<<(int)((size_t)MDIM * KDIM / 16 / 256), 256, 0, stream>>>(x, A4);
    pack_b4t_kernel<<<dim3(NDIM / 64, KDIM / 64), 256, 0, stream>>>(w, B4);
    binmm_fp4_kernel<<<dim3(NDIM / BN, MDIM / BM), 512, 0, stream>>>(A4, B4, out);
}

// Round 8
// 124.656 us; speedup vs baseline: 1.1660x; 1.1660x over previous
//
#include <hip/hip_runtime.h>
#include <stdint.h>

// C = binarize(X) @ binarize(W), exact via MX-fp4 (+-1) scaled MFMA.
// X: 8192x4096 f32, W: 4096x4096 f32, C: 8192x4096 f32.
// fp4 e2m1: +1.0 = 0x2, -1.0 = 0xA. Scale E8M0 127 = 1.0 (word 0x7F7F7F7F).
//
// R8: 256x256 tile, 8 waves (2x4), BK=256 fp4, double-buffered LDS (128 KiB),
// one barrier per K-tile. Pipeline at HALF-STEP granularity with exactly four
// live fragment sets (aC,aN,bC,bN = 64 VGPR): R7's six sets (96 VGPR) blew
// the unified VGPR/AGPR file (acc=128 AGPR; 96+50misc+128 > 256 -> scratch
// spills, +43 MB HBM traffic, 110us). Budget rule: non-acc VGPR <= ~128.
// 16x16x128 MFMA with the R5-verified ZERO-conflict LDS geometry.
#define MDIM 8192
#define NDIM 4096
#define KDIM 4096
#define KB2  (KDIM / 2)     // 2048 B per packed row (2 fp4/byte)
#define BKB  128            // K-tile bytes = 256 fp4 elems
#define NKT  (KDIM / 256)   // 16 K-tiles

#define BM 256
#define BN 256
#define ABUF      32768     // A region per buffer: 256 rows x 128 B
#define BUFSTRIDE 65536     // A + B per buffer

typedef __attribute__((ext_vector_type(4))) int   i32x4;
typedef __attribute__((ext_vector_type(8))) int   i32x8;
typedef __attribute__((ext_vector_type(4))) float f32x4;

__device__ __forceinline__ void gload16(const void* g, void* l) {
    __builtin_amdgcn_global_load_lds(
        (const __attribute__((address_space(1))) void*)g,
        (__attribute__((address_space(3))) void*)l, 16, 0, 0);
}

__device__ __forceinline__ i32x8 pad8(i32x4 v) {
    i32x8 r;
    r[0] = v[0]; r[1] = v[1]; r[2] = v[2]; r[3] = v[3];
    r[4] = 0;    r[5] = 0;    r[6] = 0;    r[7] = 0;
    return r;
}

// scale 1.0 everywhere; fp4 format code = 4 for both operands.
#define MFMA_FP4(a, b, c)                                                   \
    __builtin_amdgcn_mfma_scale_f32_16x16x128_f8f6f4(                        \
        (a), (b), (c), 4, 4, 0, 0x7F7F7F7F, 0, 0x7F7F7F7F)

// ---------------- pack X -> A4 [M][K/2] fp4 nibbles (BW-bound) ---------------
__global__ __launch_bounds__(256) void pack_a4_kernel(const float* __restrict__ X,
                                                      uint8_t* __restrict__ A4) {
    size_t gt = (size_t)blockIdx.x * 256 + threadIdx.x;
    const float4* x4 = (const float4*)X + gt * 4;
    uint32_t out[2] = {0, 0};
#pragma unroll
    for (int q = 0; q < 4; ++q) {
        float4 v = x4[q];
        uint32_t b0 = (v.x >= 0.f ? 0x2u : 0xAu) | ((v.y >= 0.f ? 0x2u : 0xAu) << 4);
        uint32_t b1 = (v.z >= 0.f ? 0x2u : 0xAu) | ((v.w >= 0.f ? 0x2u : 0xAu) << 4);
        out[q >> 1] |= (b0 | (b1 << 8)) << ((q & 1) * 16);
    }
    ((uint2*)A4)[gt] = make_uint2(out[0], out[1]);
}

// ---------------- pack W -> B4T [N][K/2] fp4 nibbles, transposed -------------
__global__ __launch_bounds__(256) void pack_b4t_kernel(const float* __restrict__ W,
                                                       uint8_t* __restrict__ B4) {
    __shared__ uint8_t t[64][72];                 // sign nibbles, +8 pad
    const int tid = threadIdx.x;
    const int k0 = blockIdx.y * 64, n0 = blockIdx.x * 64;
#pragma unroll
    for (int r = 0; r < 4; ++r) {
        int e  = r * 1024 + tid * 4;
        int k  = e >> 6;
        int nn = e & 63;
        float4 v = *(const float4*)&W[(size_t)(k0 + k) * NDIM + n0 + nn];
        uint32_t b0 = (v.x >= 0.f) ? 0x2u : 0xAu;
        uint32_t b1 = (v.y >= 0.f) ? 0x2u : 0xAu;
        uint32_t b2 = (v.z >= 0.f) ? 0x2u : 0xAu;
        uint32_t b3 = (v.w >= 0.f) ? 0x2u : 0xAu;
        *(uint32_t*)&t[k][nn] = b0 | (b1 << 8) | (b2 << 16) | (b3 << 24);
    }
    __syncthreads();
    const int n = tid >> 2, kc = tid & 3;         // 16 k-elems -> 8 bytes each
    uint32_t w[2] = {0, 0};
#pragma unroll
    for (int b = 0; b < 8; ++b) {
        int k = kc * 16 + b * 2;
        uint32_t byte = (uint32_t)t[k][n] | ((uint32_t)t[k + 1][n] << 4);
        w[b >> 2] |= byte << ((b & 3) * 8);
    }
    *(uint2*)&B4[(size_t)(n0 + n) * KB2 + k0 / 2 + kc * 8] = make_uint2(w[0], w[1]);
}

// ---------------- main: fp4 MFMA GEMM, 256x256, half-step pipelined ----------
__global__ __launch_bounds__(512, 2) void binmm_fp4_kernel(const uint8_t* __restrict__ A4,
                                                           const uint8_t* __restrict__ B4,
                                                           float* __restrict__ C) {
    __shared__ uint8_t lds[2 * BUFSTRIDE];        // 128 KiB

    const int tid = threadIdx.x, lane = tid & 63, wid = tid >> 6;
    const int wr = wid >> 2, wc = wid & 3;        // 2x4 waves; wave tile 128x64
    const int l15 = lane & 15, g = (lane >> 4) & 3;
    const int m0 = blockIdx.y * BM, n0 = blockIdx.x * BN;

    // staging: rows tid>>3 (+p*64), slot tid&7; LDS dest linear (G21),
    // source slot pre-swizzled with ^(row&7).
    const int srow  = tid >> 3;
    const int sslot = tid & 7;
    const uint8_t* gA[4];
    const uint8_t* gB[4];
#pragma unroll
    for (int p = 0; p < 4; ++p) {
        int row = srow + p * 64;
        int ss  = (sslot ^ (row & 7)) * 16;
        gA[p] = A4 + (size_t)(m0 + row) * KB2 + ss;
        gB[p] = B4 + (size_t)(n0 + row) * KB2 + ss;
    }

    f32x4 acc[8][4];
#pragma unroll
    for (int m = 0; m < 8; ++m)
#pragma unroll
        for (int n = 0; n < 4; ++n) acc[m][n] = (f32x4){0.f, 0.f, 0.f, 0.f};

    auto stageA = [&](int nxt) {
#pragma unroll
        for (int p = 0; p < 4; ++p) {
            gload16(gA[p], lds + nxt + tid * 16 + p * 8192);
            gA[p] += BKB;
        }
    };
    auto stageB = [&](int nxt) {
#pragma unroll
        for (int p = 0; p < 4; ++p) {
            gload16(gB[p], lds + nxt + ABUF + tid * 16 + p * 8192);
            gB[p] += BKB;
        }
    };

    // fragment reads, verified 0-conflict geometry: row keyed by l15,
    // slot = (s*4+g)^(row&7). half: A rows wr*128 + half*64 + {0..63}.
#define RD_A(dst, buf, s, half) do {                                           \
        _Pragma("unroll")                                                      \
        for (int mf = 0; mf < 4; ++mf) {                                       \
            int row = wr * 128 + (half) * 64 + mf * 16 + l15;                  \
            dst[mf] = *(const i32x4*)(lds + (buf) + row * 128 +                \
                                      ((((s) * 4 + g) ^ (row & 7)) * 16));     \
        }                                                                      \
    } while (0)
#define RD_B(dst, buf, s) do {                                                 \
        _Pragma("unroll")                                                      \
        for (int nf = 0; nf < 4; ++nf) {                                       \
            int row = wc * 64 + nf * 16 + l15;                                 \
            dst[nf] = *(const i32x4*)(lds + (buf) + ABUF + row * 128 +         \
                                      ((((s) * 4 + g) ^ (row & 7)) * 16));     \
        }                                                                      \
    } while (0)
    // 16-MFMA cluster: A-half `half` x all 4 B frags, acc rows half*4..+3
#define CLUSTER(AS, BS, half) do {                                             \
        __builtin_amdgcn_s_setprio(1);                                         \
        _Pragma("unroll")                                                      \
        for (int mf = 0; mf < 4; ++mf) {                                       \
            i32x8 a8 = pad8(AS[mf]);                                           \
            acc[(half) * 4 + mf][0] = MFMA_FP4(a8, pad8(BS[0]), acc[(half) * 4 + mf][0]); \
            acc[(half) * 4 + mf][1] = MFMA_FP4(a8, pad8(BS[1]), acc[(half) * 4 + mf][1]); \
            acc[(half) * 4 + mf][2] = MFMA_FP4(a8, pad8(BS[2]), acc[(half) * 4 + mf][2]); \
            acc[(half) * 4 + mf][3] = MFMA_FP4(a8, pad8(BS[3]), acc[(half) * 4 + mf][3]); \
        }                                                                      \
        __builtin_amdgcn_s_setprio(0);                                         \
    } while (0)

    // exactly 4 live fragment sets (64 VGPR): current/next A, current/next B
    i32x4 aC[4], aN[4], bC[4], bN[4];

    // one K-tile: 4 half-step phases; entering, bC=B(cur,s0), aC=A(cur,s0,lo).
    auto tile = [&](int cur, int nxt, bool do_stage, bool rd_next) {
        // h0: prefetch A(s0,hi); stage A(nxt); compute lo x B(s0)
        RD_A(aN, cur, 0, 1);
        if (do_stage) stageA(nxt);
        CLUSTER(aC, bC, 0);
        // h1: prefetch B(s1), A(s1,lo); stage B(nxt); compute hi x B(s0)
        RD_B(bN, cur, 1);
        RD_A(aC, cur, 1, 0);
        if (do_stage) stageB(nxt);
        CLUSTER(aN, bC, 1);
        // h2: prefetch A(s1,hi); compute lo x B(s1)
        RD_A(aN, cur, 1, 1);
        CLUSTER(aC, bN, 0);
        // h3: compute hi x B(s1)
        CLUSTER(aN, bN, 1);
        // barrier: publishes cur free; waits nxt stage loads (vmcnt drain)
        __syncthreads();
        if (rd_next) {
            RD_B(bC, nxt, 0);
            RD_A(aC, nxt, 0, 0);
        }
    };

    // prologue: stage tile 0 into buffer 0, then read its s=0 frags
    stageA(0); stageB(0);
    __syncthreads();
    RD_B(bC, 0, 0);
    RD_A(aC, 0, 0, 0);

#pragma unroll 1
    for (int tt = 0; tt < NKT / 2 - 1; ++tt) {    // tiles 0..13
        tile(0, BUFSTRIDE, true, true);
        tile(BUFSTRIDE, 0, true, true);
    }
    tile(0, BUFSTRIDE, true, true);               // tile 14 (stages tile 15)
    tile(BUFSTRIDE, 0, false, false);             // tile 15

    // epilogue: C/D 16x16 layout: col = lane&15, row = (lane>>4)*4 + reg
#pragma unroll
    for (int mf = 0; mf < 8; ++mf) {
#pragma unroll
        for (int nf = 0; nf < 4; ++nf) {
            size_t cc = (size_t)(n0 + wc * 64 + nf * 16 + l15);
            int rbase = m0 + wr * 128 + mf * 16 + g * 4;
#pragma unroll
            for (int reg = 0; reg < 4; ++reg)
                C[(size_t)(rbase + reg) * NDIM + cc] = acc[mf][nf][reg];
        }
    }
}

// =============================================================================
extern "C" void kernel_launch(void* const* d_in, const int* in_sizes, int n_in,
                              void* d_out, int out_size, void* d_ws, size_t ws_size,
                              hipStream_t stream) {
    const float* x = (const float*)d_in[0];   // [8192][4096]
    const float* w = (const float*)d_in[1];   // [4096][4096]
    float* out = (float*)d_out;               // [8192][4096]

    // workspace: A4 [M][K/2] (16 MiB) then B4T [N][K/2] (8 MiB)
    uint8_t* A4 = (uint8_t*)d_ws;
    uint8_t* B4 = (uint8_t*)d_ws + (size_t)MDIM * KB2;

    pack_a4_kernel<<<(int)((size_t)MDIM * KDIM / 16 / 256), 256, 0, stream>>>(x, A4);
    pack_b4t_kernel<<<dim3(NDIM / 64, KDIM / 64), 256, 0, stream>>>(w, B4);
    binmm_fp4_kernel<<<dim3(NDIM / BN, MDIM / BM), 512, 0, stream>>>(A4, B4, out);
}